// Round 6
// baseline (131.474 us; speedup 1.0000x reference)
//
#include <hip/hip_runtime.h>
#include <math.h>

typedef float f4 __attribute__((ext_vector_type(4)));
typedef int   i2 __attribute__((ext_vector_type(2)));

#define NCg 128
#define NAg 65
#define KNUM 128
#define PDIM 64
#define EDIM 256
#define NEDGE (NCg*NAg*NAg)      // 540800
#define NROWS (NCg*NAg)          // 8320
#define TLO -8.0f
#define TSPAN 144                // xs domain [-8,136]; clamped outside
#define TPTS 4                   // table grid points per block
#define WTP 260                  // wt_s padded row stride (floats): 1040B, 16B-aligned,
                                 // read rows conflict-free, write side 4-way (free-ish)

// ---------------------------------------------------------------------------
// Kernel A: build g_d(xs) table.  (unchanged from round 4 — verified fast)
// ---------------------------------------------------------------------------
__launch_bounds__(128)
__global__ void table_kernel(const float* __restrict__ mean,
                             const float* __restrict__ w1,
                             const float* __restrict__ b1,
                             const float* __restrict__ w2,
                             const float* __restrict__ b2,
                             float* __restrict__ T,
                             float invres, int npt)
{
    __shared__ f4 wbuf[128*17];          // 34.8KB; w1 half [128 rows][16+1 f4]
                                         // reused for w2 as [64 rows][32+1 f4]
    __shared__ f4 gb4[KNUM];
    __shared__ f4 h4[KNUM];

    const int t  = threadIdx.x;          // 128 threads
    const int p0 = blockIdx.x * TPTS;

    const float stdv     = mean[1] - mean[0];
    const float inv_astd = 1.0f / (sqrtf(6.28318f) * stdv);

    {
        f4 g;
        float u0 = TLO + (float)(p0+0)*invres - (float)t;
        float u1 = TLO + (float)(p0+1)*invres - (float)t;
        float u2 = TLO + (float)(p0+2)*invres - (float)t;
        float u3 = TLO + (float)(p0+3)*invres - (float)t;
        g.x = expf(-0.5f*u0*u0) * inv_astd;
        g.y = expf(-0.5f*u1*u1) * inv_astd;
        g.z = expf(-0.5f*u2*u2) * inv_astd;
        g.w = expf(-0.5f*u3*u3) * inv_astd;
        gb4[t] = g;
    }

    f4 acc = {0.f, 0.f, 0.f, 0.f};
    for (int H = 0; H < 2; ++H) {
        __syncthreads();
        for (int it = 0; it < 16; ++it) {
            int u   = t + 128*it;
            int row = u >> 4;
            int c4  = u & 15;
            wbuf[row*17 + c4] = ((const f4*)w1)[row*32 + H*16 + c4];
        }
        __syncthreads();
        const f4* wr = &wbuf[t*17];
        #pragma unroll
        for (int kq = 0; kq < 16; ++kq) {
            f4 wv = wr[kq];
            int kb = H*64 + kq*4;
            acc = acc + wv.x * gb4[kb+0];
            acc = acc + wv.y * gb4[kb+1];
            acc = acc + wv.z * gb4[kb+2];
            acc = acc + wv.w * gb4[kb+3];
        }
    }
    {
        float b1t = b1[t];
        f4 hv;
        hv.x = 0.5f*acc.x*(1.0f + erff(acc.x*0.70710678118654752f)) + b1t;
        hv.y = 0.5f*acc.y*(1.0f + erff(acc.y*0.70710678118654752f)) + b1t;
        hv.z = 0.5f*acc.z*(1.0f + erff(acc.z*0.70710678118654752f)) + b1t;
        hv.w = 0.5f*acc.w*(1.0f + erff(acc.w*0.70710678118654752f)) + b1t;
        h4[t] = hv;
    }
    __syncthreads();
    for (int it = 0; it < 16; ++it) {
        int u   = t + 128*it;
        int row = u >> 5;
        int c4  = u & 31;
        wbuf[row*33 + c4] = ((const f4*)w2)[u];
    }
    __syncthreads();

    if (t < PDIM) {
        float b2t = b2[t];
        f4 o = {b2t, b2t, b2t, b2t};
        const f4* wr = &wbuf[t*33];
        #pragma unroll
        for (int kq = 0; kq < 32; ++kq) {
            f4 wv = wr[kq];
            o = o + wv.x * h4[kq*4+0];
            o = o + wv.y * h4[kq*4+1];
            o = o + wv.z * h4[kq*4+2];
            o = o + wv.w * h4[kq*4+3];
        }
        if (p0+0 < npt) T[(size_t)(p0+0)*PDIM + t] = o.x;
        if (p0+1 < npt) T[(size_t)(p0+1)*PDIM + t] = o.y;
        if (p0+2 < npt) T[(size_t)(p0+2)*PDIM + t] = o.z;
        if (p0+3 < npt) T[(size_t)(p0+3)*PDIM + t] = o.w;
    }
}

// ---------------------------------------------------------------------------
// Kernel B: atom path.  16 rows/block.
// v5 GEMM phase: 4rr x 4d register tile per thread (a=t>>6 -> rr quad,
// b=t&63 -> d quad); ep_w staged TRANSPOSED into LDS in 32-k chunks
// (coalesced f4 global reads; padded stride WTP keeps read rows 16B-aligned
// + conflict-free).  Replaces 512-B-stride ep_w reads (64 cache lines per
// wave load) and the 512-broadcast LDS pattern.
// ---------------------------------------------------------------------------
__launch_bounds__(256)
__global__ void atom_kernel(const float* __restrict__ coord,
                            const float* __restrict__ atom_feat,
                            const int*   __restrict__ etype,
                            const float* __restrict__ mul_w,
                            const float* __restrict__ bias_w,
                            const float* __restrict__ mean,
                            const float* __restrict__ ep_w,
                            const float* __restrict__ ep_b,
                            float* __restrict__ out_atom)
{
    __shared__ float x_s[16*NAg];        //  4.2 KB
    __shared__ float sum_s[16*KNUM];     //  8.0 KB
    __shared__ float wt_s[32*WTP];       // 33.3 KB -> total 45.6 KB, 3 blk/CU

    const int t  = threadIdx.x;
    const int r0 = blockIdx.x * 16;

    const float stdv     = mean[1] - mean[0];
    const float inv_std  = 1.0f / stdv;
    const float inv_astd = 1.0f / (sqrtf(6.28318f) * stdv);

    for (int it = 0; it < 5; ++it) {
        int item = t + 256*it;
        if (item < 16*NAg) {
            int rr = item / NAg;
            int j  = item - rr*NAg;
            int r  = r0 + rr;
            int c  = r / NAg;
            int i  = r - c*NAg;
            const float* ci = coord + (c*NAg + i)*3;
            const float* cj = coord + (c*NAg + j)*3;
            float dx = cj[0]-ci[0], dy = cj[1]-ci[1], dz = cj[2]-ci[2];
            float dist = sqrtf(dx*dx + dy*dy + dz*dz);
            int t0 = etype[(r*NAg+j)*2+0], t1 = etype[(r*NAg+j)*2+1];
            float mul  = fabsf(mul_w[t0]) + fabsf(mul_w[t1]);
            float bias = bias_w[t0] + bias_w[t1];
            x_s[item] = (mul*dist + bias) * inv_std;
        }
    }
    __syncthreads();

    for (int it = 0; it < 8; ++it) {
        int item = t + 256*it;              // 16*128 = 2048
        int rr = item >> 7;
        int k  = item & 127;
        float fk = (float)k;
        const float* xr = &x_s[rr*NAg];
        float a0=0.f, a1=0.f, a2=0.f, a3=0.f;
        int j = 0;
        for (; j <= NAg-4; j += 4) {
            float u0 = xr[j+0]-fk, u1 = xr[j+1]-fk, u2 = xr[j+2]-fk, u3 = xr[j+3]-fk;
            a0 += exp2f(u0*u0 * -0.72134752f);
            a1 += exp2f(u1*u1 * -0.72134752f);
            a2 += exp2f(u2*u2 * -0.72134752f);
            a3 += exp2f(u3*u3 * -0.72134752f);
        }
        for (; j < NAg; ++j) {
            float u0 = xr[j]-fk;
            a0 += exp2f(u0*u0 * -0.72134752f);
        }
        sum_s[item] = ((a0+a1)+(a2+a3)) * inv_astd;
    }

    // ---- phase 3: C[16][256] = S[16][128] @ W^T, 4rr x 4d per thread ----
    const int a = t >> 6;      // rr quad (const per wave -> sum_s reads are
    const int b = t & 63;      //           full-wave broadcasts)
    f4 acc0 = {0,0,0,0}, acc1 = {0,0,0,0}, acc2 = {0,0,0,0}, acc3 = {0,0,0,0};

    for (int ch = 0; ch < 4; ++ch) {   // 4 chunks of 32 k
        __syncthreads();               // protects wt_s reuse (and phase-2 on ch=0)
        // stage ep_w[0..255][ch*32 .. +31] transposed -> wt_s[k][d]
        for (int it = 0; it < 8; ++it) {
            int u  = t + 256*it;       // 0..2047
            int d  = u >> 3;
            int c4 = u & 7;
            f4 wv = *(const f4*)&ep_w[d*KNUM + ch*32 + c4*4];
            wt_s[(c4*4+0)*WTP + d] = wv.x;
            wt_s[(c4*4+1)*WTP + d] = wv.y;
            wt_s[(c4*4+2)*WTP + d] = wv.z;
            wt_s[(c4*4+3)*WTP + d] = wv.w;
        }
        __syncthreads();
        #pragma unroll
        for (int kq = 0; kq < 8; ++kq) {
            f4 s0 = *(const f4*)&sum_s[(4*a+0)*KNUM + ch*32 + kq*4];
            f4 s1 = *(const f4*)&sum_s[(4*a+1)*KNUM + ch*32 + kq*4];
            f4 s2 = *(const f4*)&sum_s[(4*a+2)*KNUM + ch*32 + kq*4];
            f4 s3 = *(const f4*)&sum_s[(4*a+3)*KNUM + ch*32 + kq*4];
            #define GSTEP(j, comp) { \
                f4 wv = *(const f4*)&wt_s[(kq*4+j)*WTP + 4*b]; \
                acc0 = acc0 + s0.comp * wv; acc1 = acc1 + s1.comp * wv; \
                acc2 = acc2 + s2.comp * wv; acc3 = acc3 + s3.comp * wv; }
            GSTEP(0, x) GSTEP(1, y) GSTEP(2, z) GSTEP(3, w)
            #undef GSTEP
        }
    }

    {
        f4 epb = *(const f4*)&ep_b[4*b];
        f4 av[4] = {acc0, acc1, acc2, acc3};
        #pragma unroll
        for (int q = 0; q < 4; ++q) {
            int o = (r0 + 4*a + q)*EDIM + 4*b;
            f4 af = __builtin_nontemporal_load((const f4*)&atom_feat[o]);
            __builtin_nontemporal_store(af + av[q] + epb, (f4*)&out_atom[o]);
        }
    }
}

// ---------------------------------------------------------------------------
// Kernel C: attn stream + delta.  Block = 128 edges, barrier-free main path.
// v5: ef + etype loads nontemporal so the 138MB stream doesn't evict the
// 590KB T table from L2.  (etype via clang ext-vector i2 — HIP's int2 struct
// is rejected by __builtin_nontemporal_load.)
// ---------------------------------------------------------------------------
__launch_bounds__(256)
__global__ void attn_kernel(const float* __restrict__ coord,
                            const int*   __restrict__ etype,
                            const float* __restrict__ mul_w,
                            const float* __restrict__ bias_w,
                            const float* __restrict__ mean,
                            const float* __restrict__ edge_feat,
                            const float* __restrict__ T,
                            float fres, int npt,
                            float* __restrict__ out_attn,
                            float* __restrict__ out_delta)
{
    __shared__ __attribute__((aligned(16))) float dl[128*3];

    const int t  = threadIdx.x;
    const int dq = t & 15;
    const int er = t >> 4;                        // 0..15
    const size_t u0 = (size_t)blockIdx.x * 2048;  // f4 units
    const int e0 = blockIdx.x * 128;

    const float inv_std = 1.0f / (mean[1] - mean[0]);

    // ---- edge_feature loads first: longest-latency, fully independent ----
    f4 ef[8];
    #pragma unroll
    for (int p = 0; p < 8; ++p)
        ef[p] = __builtin_nontemporal_load((const f4*)edge_feat + u0 + p*256 + t);

    // ---- inline meta -> xs (16-lane redundant, no barrier), delta to LDS --
    float xsv[8];
    #pragma unroll
    for (int p = 0; p < 8; ++p) {
        int eg  = e0 + p*16 + er;
        int c   = eg / (NAg*NAg);
        int rem = eg - c*(NAg*NAg);
        int i   = rem / NAg;
        int j   = rem - i*NAg;
        const float* ci = coord + (c*NAg + i)*3;
        const float* cj = coord + (c*NAg + j)*3;
        float dx = cj[0]-ci[0], dy = cj[1]-ci[1], dz = cj[2]-ci[2];
        if (dq < 3) dl[(p*16+er)*3 + dq] = (dq==0) ? dx : ((dq==1) ? dy : dz);
        float dist = sqrtf(dx*dx + dy*dy + dz*dz);
        i2 tp = __builtin_nontemporal_load((const i2*)&etype[(size_t)eg*2]);
        float mul  = fabsf(mul_w[tp.x]) + fabsf(mul_w[tp.y]);
        float bias = bias_w[tp.x] + bias_w[tp.y];
        xsv[p] = (mul*dist + bias) * inv_std;
    }

    int idx[8]; float fr[8];
    #pragma unroll
    for (int p = 0; p < 8; ++p) {
        float ti = (xsv[p] - TLO) * fres;
        int   i  = (int)ti;
        i = i < 0 ? 0 : (i > npt-2 ? npt-2 : i);
        float f = ti - (float)i;
        fr[p]  = f < 0.0f ? 0.0f : (f > 1.0f ? 1.0f : f);
        idx[p] = i;
    }

    // ---- per 4-edge group: gather + lerp + add + nt store ----
    #pragma unroll
    for (int g = 0; g < 2; ++g) {
        f4 lo[4], hi[4];
        #pragma unroll
        for (int q = 0; q < 4; ++q) {
            int p = g*4 + q;
            const float* tr = T + (size_t)idx[p]*PDIM + dq*4;
            lo[q] = *(const f4*)tr;
            hi[q] = *(const f4*)(tr + PDIM);
        }
        #pragma unroll
        for (int q = 0; q < 4; ++q) {
            int p = g*4 + q;
            f4 o;
            o.x = fmaf(fr[p], hi[q].x - lo[q].x, lo[q].x) + ef[p].x;
            o.y = fmaf(fr[p], hi[q].y - lo[q].y, lo[q].y) + ef[p].y;
            o.z = fmaf(fr[p], hi[q].z - lo[q].z, lo[q].z) + ef[p].z;
            o.w = fmaf(fr[p], hi[q].w - lo[q].w, lo[q].w) + ef[p].w;
            __builtin_nontemporal_store(o, (f4*)out_attn + u0 + p*256 + t);
        }
    }

    // ---- delta_pos: 384 floats = 96 coalesced f4 nt stores ----
    __syncthreads();
    if (t < 96) {
        f4 dv = *(const f4*)&dl[t*4];
        __builtin_nontemporal_store(dv, (f4*)(out_delta) + (size_t)blockIdx.x*96 + t);
    }
}

extern "C" void kernel_launch(void* const* d_in, const int* in_sizes, int n_in,
                              void* d_out, int out_size, void* d_ws, size_t ws_size,
                              hipStream_t stream) {
    const float* coord     = (const float*)d_in[0];
    const float* atom_feat = (const float*)d_in[1];
    const int*   etype     = (const int*)  d_in[2];
    const float* edge_feat = (const float*)d_in[3];
    const float* mul_w     = (const float*)d_in[4];
    const float* bias_w    = (const float*)d_in[5];
    const float* mean      = (const float*)d_in[6];
    const float* w1        = (const float*)d_in[7];
    const float* b1        = (const float*)d_in[8];
    const float* w2        = (const float*)d_in[9];
    const float* b2        = (const float*)d_in[10];
    const float* ep_w      = (const float*)d_in[11];
    const float* ep_b      = (const float*)d_in[12];

    float* out = (float*)d_out;
    float* out_atom  = out;
    float* out_attn  = out + (size_t)NCg*NAg*EDIM;
    float* out_delta = out + (size_t)NCg*NAg*EDIM + (size_t)NEDGE*PDIM;

    auto tblBytes = [](int res){ return (size_t)(TSPAN*res+1)*PDIM*4; };
    int res;
    if      (ws_size >= tblBytes(16)) res = 16;   // 590 KB
    else if (ws_size >= tblBytes(4))  res = 4;
    else                              res = 1;
    int npt = TSPAN*res + 1;
    float* Tbl = (float*)d_ws;

    table_kernel<<<(npt + TPTS - 1)/TPTS, 128, 0, stream>>>(
        mean, w1, b1, w2, b2, Tbl, 1.0f/(float)res, npt);

    atom_kernel<<<NROWS/16, 256, 0, stream>>>(
        coord, atom_feat, etype, mul_w, bias_w, mean, ep_w, ep_b, out_atom);

    attn_kernel<<<NEDGE/128, 256, 0, stream>>>(
        coord, etype, mul_w, bias_w, mean, edge_feat, Tbl,
        (float)res, npt, out_attn, out_delta);
}